// Round 2
// baseline (624.655 us; speedup 1.0000x reference)
//
#include <hip/hip_runtime.h>

#define TT 512
#define II 10
#define HH 32
#define KH 16   // h-elements per lane-half
#define IH 5    // x-elements per lane-half

#define LOG2E 1.44269504088896340736f

__device__ __forceinline__ float frcp(float v) { return __builtin_amdgcn_rcpf(v); }
// sigmoid via exp2: 1/(1+2^(-x*log2e))
__device__ __forceinline__ float sigm(float v) { return frcp(1.0f + exp2f(-LOG2E * v)); }
// tanh via sigmoid: 2/(1+2^(-2x*log2e)) - 1
__device__ __forceinline__ float tanh_f(float v) { return 2.0f * frcp(1.0f + exp2f(-2.0f * LOG2E * v)) - 1.0f; }

// Layout: wave = 1 batch row. lane = (unit j = lane&31, k-half kh = lane>>5).
// Each thread computes ALL 4 gates for unit j, but only over h[kh*16..+16) and
// x[kh*5..+5) -> 84 weight floats/thread (~120 VGPRs total), fits the 128-VGPR
// 4-waves/SIMD tier with no AGPR shuffling. Partial gate sums combine across
// halves with shfl_xor(32); both halves then redundantly compute the (identical)
// activations and state update -> uniform control flow, no second exchange.
// Each wave owns its row's h slots in LDS -> no __syncthreads anywhere.
extern "C" __global__ __launch_bounds__(256, 4)
void lstm_fused(const float* __restrict__ x,
                const float* __restrict__ h0,
                const float* __restrict__ c0,
                const float* __restrict__ W_ih,
                const float* __restrict__ W_hh,
                const float* __restrict__ b_ih,
                const float* __restrict__ b_hh,
                const float* __restrict__ W_lin,
                const float* __restrict__ b_lin,
                float* __restrict__ out)
{
    __shared__ float h_lds[4][HH];

    const int tid  = threadIdx.x;
    const int wv   = tid >> 6;
    const int lane = tid & 63;
    const int kh   = lane >> 5;      // which k/input half this thread sums
    const int j    = lane & 31;      // hidden unit owned by this thread
    const int b    = blockIdx.x * 4 + wv;

    // ---- weights into registers: 4 gates x (16 h-weights + 5 x-weights) ----
    float w[4][KH];
    float wi[4][IH];
    float bias[4];
    #pragma unroll
    for (int g = 0; g < 4; ++g) {
        const int row = g * HH + j;
        const float4* wr = reinterpret_cast<const float4*>(W_hh + row * HH + kh * KH);
        #pragma unroll
        for (int k4 = 0; k4 < KH / 4; ++k4) {
            const float4 v = wr[k4];
            w[g][4 * k4 + 0] = v.x; w[g][4 * k4 + 1] = v.y;
            w[g][4 * k4 + 2] = v.z; w[g][4 * k4 + 3] = v.w;
        }
        const float* wir = W_ih + row * II + kh * IH;
        #pragma unroll
        for (int i = 0; i < IH; ++i) wi[g][i] = wir[i];
        // bias added on kh==0 partial only (would double after combine otherwise)
        bias[g] = (kh == 0) ? (b_ih[row] + b_hh[row]) : 0.0f;
    }

    float c = c0[b * HH + j];        // identical on both halves
    h_lds[wv][j] = h0[b * HH + j];   // lanes j and j+32 write same value: benign

    const float* xrow = x + (size_t)b * (TT * II) + kh * IH;

    // prefetch x[t=0] (this half's 5 elements)
    float xv[IH];
    #pragma unroll
    for (int i = 0; i < IH; ++i) xv[i] = xrow[i];

    float hv = 0.0f;
    for (int t = 0; t < TT; ++t) {
        // software-prefetch next step's x (clamped, branchless)
        float xn[IH];
        {
            const int tn = (t + 1 < TT) ? (t + 1) : t;
            const float* xp = xrow + tn * II;
            #pragma unroll
            for (int i = 0; i < IH; ++i) xn[i] = xp[i];
        }

        float a0 = bias[0], a1 = bias[1], a2 = bias[2], a3 = bias[3];

        // input projection partial: 20 FMAs
        #pragma unroll
        for (int i = 0; i < IH; ++i) {
            const float xi = xv[i];
            a0 += wi[0][i] * xi;
            a1 += wi[1][i] * xi;
            a2 += wi[2][i] * xi;
            a3 += wi[3][i] * xi;
        }

        // recurrent projection partial over this half's 16 h-elements: 64 FMAs.
        // All 32 lanes of a half read the same address -> LDS broadcast;
        // the two halves hit disjoint banks -> conflict-free.
        #pragma unroll
        for (int k4 = 0; k4 < KH / 4; ++k4) {
            const float4 h4 = *reinterpret_cast<const float4*>(&h_lds[wv][kh * KH + 4 * k4]);
            const float h0v = h4.x, h1v = h4.y, h2v = h4.z, h3v = h4.w;
            a0 += w[0][4 * k4 + 0] * h0v; a1 += w[1][4 * k4 + 0] * h0v;
            a2 += w[2][4 * k4 + 0] * h0v; a3 += w[3][4 * k4 + 0] * h0v;
            a0 += w[0][4 * k4 + 1] * h1v; a1 += w[1][4 * k4 + 1] * h1v;
            a2 += w[2][4 * k4 + 1] * h1v; a3 += w[3][4 * k4 + 1] * h1v;
            a0 += w[0][4 * k4 + 2] * h2v; a1 += w[1][4 * k4 + 2] * h2v;
            a2 += w[2][4 * k4 + 2] * h2v; a3 += w[3][4 * k4 + 2] * h2v;
            a0 += w[0][4 * k4 + 3] * h3v; a1 += w[1][4 * k4 + 3] * h3v;
            a2 += w[2][4 * k4 + 3] * h3v; a3 += w[3][4 * k4 + 3] * h3v;
        }

        // combine the two halves' partials: both halves end with full sums
        a0 += __shfl_xor(a0, 32);
        a1 += __shfl_xor(a1, 32);
        a2 += __shfl_xor(a2, 32);
        a3 += __shfl_xor(a3, 32);

        // gates + state (computed identically on both halves: uniform flow)
        const float ig = sigm(a0);
        const float fg = sigm(a1);
        const float gg = tanh_f(a2);
        const float og = sigm(a3);
        c  = fg * c + ig * gg;
        hv = og * tanh_f(c);
        h_lds[wv][j] = hv;           // both halves store same value; in-wave DS order

        #pragma unroll
        for (int i = 0; i < IH; ++i) xv[i] = xn[i];
    }

    // out[b] = dot(hT, W_lin) + b_lin -- butterfly within the 32-lane half
    float p = hv * W_lin[j];
    p += __shfl_xor(p, 1);
    p += __shfl_xor(p, 2);
    p += __shfl_xor(p, 4);
    p += __shfl_xor(p, 8);
    p += __shfl_xor(p, 16);
    if (lane == 0) out[b] = p + b_lin[0];
}

extern "C" void kernel_launch(void* const* d_in, const int* in_sizes, int n_in,
                              void* d_out, int out_size, void* d_ws, size_t ws_size,
                              hipStream_t stream) {
    const float* x     = (const float*)d_in[0];
    const float* h0    = (const float*)d_in[1];
    const float* c0    = (const float*)d_in[2];
    const float* W_ih  = (const float*)d_in[3];
    const float* W_hh  = (const float*)d_in[4];
    const float* b_ih  = (const float*)d_in[5];
    const float* b_hh  = (const float*)d_in[6];
    const float* W_lin = (const float*)d_in[7];
    const float* b_lin = (const float*)d_in[8];
    float* out = (float*)d_out;

    const int B = in_sizes[1] / HH;   // 4096
    dim3 grid(B / 4), block(256);
    lstm_fused<<<grid, block, 0, stream>>>(x, h0, c0, W_ih, W_hh, b_ih, b_hh, W_lin, b_lin, out);
}

// Round 3
// 409.666 us; speedup vs baseline: 1.5248x; 1.5248x over previous
//
#include <hip/hip_runtime.h>

#define TT 512
#define II 10
#define HH 32

typedef float v2f __attribute__((ext_vector_type(2)));

__device__ __forceinline__ float frcp(float v) { return __builtin_amdgcn_rcpf(v); }
__device__ __forceinline__ float sigm(float v) { return frcp(1.0f + __expf(-v)); }
__device__ __forceinline__ float tanh_f(float v) { return 1.0f - 2.0f * frcp(__expf(2.0f * v) + 1.0f); }

// Layout (back to R1's transc-efficient shape): wave = 2 batch rows x 32 units,
// thread = (row, unit j). Each thread holds unit j's FULL weight set as float2
// GATE-PAIRS: w01[k]=(W_i, W_f), w23[k]=(W_g, W_o) -> v_pk_fma_f32 does 2 FMAs
// per instr with no weight splat. h/x operands splat ({h,h}) at <=1 mov each.
// ~205 live floats/thread: amdgpu_waves_per_eu(2,2) pins the allocator to the
// 256-VGPR budget so weights STAY in registers (R1/R2 regressed because the
// allocator chased a higher-occupancy tier and sank weight loads into the loop).
// Grid 512 blocks = 2 blocks/CU fills exactly 2 waves/SIMD.
// Each wave owns its 2 rows' h slots in LDS -> no __syncthreads in the loop.
extern "C" __global__ __launch_bounds__(256)
__attribute__((amdgpu_waves_per_eu(2, 2)))
void lstm_fused(const float* __restrict__ x,
                const float* __restrict__ h0,
                const float* __restrict__ c0,
                const float* __restrict__ W_ih,
                const float* __restrict__ W_hh,
                const float* __restrict__ b_ih,
                const float* __restrict__ b_hh,
                const float* __restrict__ W_lin,
                const float* __restrict__ b_lin,
                float* __restrict__ out)
{
    __shared__ float h_lds[8][HH];

    const int tid = threadIdx.x;
    const int bl  = tid >> 5;        // local row 0..7 (= wave*2 + half)
    const int j   = tid & 31;        // hidden unit owned by this thread
    const int b   = blockIdx.x * 8 + bl;

    // ---- weights as gate-paired float2 in registers ----
    v2f w01[HH], w23[HH];    // (W_hh[i-row][k], W_hh[f-row][k]) / (g,o)
    v2f wi01[II], wi23[II];
    v2f bias01, bias23;
    {
        const float* r0 = W_hh + (0 * HH + j) * HH;
        const float* r1 = W_hh + (1 * HH + j) * HH;
        const float* r2 = W_hh + (2 * HH + j) * HH;
        const float* r3 = W_hh + (3 * HH + j) * HH;
        #pragma unroll
        for (int k = 0; k < HH; ++k) {
            w01[k] = v2f{r0[k], r1[k]};
            w23[k] = v2f{r2[k], r3[k]};
        }
        const float* q0 = W_ih + (0 * HH + j) * II;
        const float* q1 = W_ih + (1 * HH + j) * II;
        const float* q2 = W_ih + (2 * HH + j) * II;
        const float* q3 = W_ih + (3 * HH + j) * II;
        #pragma unroll
        for (int i = 0; i < II; ++i) {
            wi01[i] = v2f{q0[i], q1[i]};
            wi23[i] = v2f{q2[i], q3[i]};
        }
        bias01 = v2f{b_ih[0 * HH + j] + b_hh[0 * HH + j],
                     b_ih[1 * HH + j] + b_hh[1 * HH + j]};
        bias23 = v2f{b_ih[2 * HH + j] + b_hh[2 * HH + j],
                     b_ih[3 * HH + j] + b_hh[3 * HH + j]};
    }

    float c = c0[b * HH + j];
    h_lds[bl][j] = h0[b * HH + j];   // same-wave RAW; LDS in-order per wave
    float hv = 0.0f;

    const float* xrow = x + (size_t)b * (TT * II);

    float xa[II], xb[II];            // ping-pong x buffers (no copy loop)
    {
        const float2* x2 = reinterpret_cast<const float2*>(xrow);
        #pragma unroll
        for (int i = 0; i < II / 2; ++i) { float2 v = x2[i]; xa[2*i] = v.x; xa[2*i+1] = v.y; }
    }

    #define PREFETCH(buf, tnext)                                             \
        {                                                                    \
            const int tn_ = (tnext) < TT ? (tnext) : (TT - 1);               \
            const float2* x2_ = reinterpret_cast<const float2*>(xrow + tn_ * II); \
            _Pragma("unroll")                                                \
            for (int i_ = 0; i_ < II / 2; ++i_) {                            \
                float2 v_ = x2_[i_]; (buf)[2*i_] = v_.x; (buf)[2*i_+1] = v_.y; \
            }                                                                \
        }

    #define STEP(xv)                                                         \
        {                                                                    \
            v2f a01 = bias01, a23 = bias23;                                  \
            _Pragma("unroll")                                                \
            for (int i = 0; i < II; ++i) {                                   \
                const v2f xs = v2f{(xv)[i], (xv)[i]};                        \
                a01 = __builtin_elementwise_fma(wi01[i], xs, a01);           \
                a23 = __builtin_elementwise_fma(wi23[i], xs, a23);           \
            }                                                                \
            _Pragma("unroll")                                                \
            for (int k4 = 0; k4 < HH / 4; ++k4) {                            \
                const float4 h4 = *reinterpret_cast<const float4*>(&h_lds[bl][4 * k4]); \
                v2f s;                                                       \
                s = v2f{h4.x, h4.x};                                         \
                a01 = __builtin_elementwise_fma(w01[4*k4+0], s, a01);        \
                a23 = __builtin_elementwise_fma(w23[4*k4+0], s, a23);        \
                s = v2f{h4.y, h4.y};                                         \
                a01 = __builtin_elementwise_fma(w01[4*k4+1], s, a01);        \
                a23 = __builtin_elementwise_fma(w23[4*k4+1], s, a23);        \
                s = v2f{h4.z, h4.z};                                         \
                a01 = __builtin_elementwise_fma(w01[4*k4+2], s, a01);        \
                a23 = __builtin_elementwise_fma(w23[4*k4+2], s, a23);        \
                s = v2f{h4.w, h4.w};                                         \
                a01 = __builtin_elementwise_fma(w01[4*k4+3], s, a01);        \
                a23 = __builtin_elementwise_fma(w23[4*k4+3], s, a23);        \
            }                                                                \
            const float ig = sigm(a01.x);                                    \
            const float fg = sigm(a01.y);                                    \
            const float gg = tanh_f(a23.x);                                  \
            const float og = sigm(a23.y);                                    \
            c  = fg * c + ig * gg;                                           \
            hv = og * tanh_f(c);                                             \
            h_lds[bl][j] = hv;                                               \
        }

    for (int t = 0; t < TT; t += 2) {
        PREFETCH(xb, t + 1);
        STEP(xa);
        PREFETCH(xa, t + 2);
        STEP(xb);
    }
    #undef STEP
    #undef PREFETCH

    // out[b] = dot(hT, W_lin) + b_lin -- butterfly within each 32-lane half
    float p = hv * W_lin[j];
    p += __shfl_xor(p, 1);
    p += __shfl_xor(p, 2);
    p += __shfl_xor(p, 4);
    p += __shfl_xor(p, 8);
    p += __shfl_xor(p, 16);
    if (j == 0) out[b] = p + b_lin[0];
}

extern "C" void kernel_launch(void* const* d_in, const int* in_sizes, int n_in,
                              void* d_out, int out_size, void* d_ws, size_t ws_size,
                              hipStream_t stream) {
    const float* x     = (const float*)d_in[0];
    const float* h0    = (const float*)d_in[1];
    const float* c0    = (const float*)d_in[2];
    const float* W_ih  = (const float*)d_in[3];
    const float* W_hh  = (const float*)d_in[4];
    const float* b_ih  = (const float*)d_in[5];
    const float* b_hh  = (const float*)d_in[6];
    const float* W_lin = (const float*)d_in[7];
    const float* b_lin = (const float*)d_in[8];
    float* out = (float*)d_out;

    const int B = in_sizes[1] / HH;   // 4096
    dim3 grid(B / 8), block(256);
    lstm_fused<<<grid, block, 0, stream>>>(x, h0, c0, W_ih, W_hh, b_ih, b_hh, W_lin, b_lin, out);
}